// Round 2
// baseline (32.027 us; speedup 1.0000x reference)
//
#include <hip/hip_runtime.h>
#include <math.h>

#define Bn 16
#define Cn 10
#define Hn 400
#define Wn 352
#define Nn 50
#define PLANE (Hn * Wn)          // 140800 floats, 35200 float4
#define NCHUNK 32
#define VPER (PLANE / 4 / NCHUNK)   // 1100 float4 per chunk
#define BKG_THRESH 0.025f
#define LOG_CLAMP -100.0f

// stable log(1+exp(x))
__device__ __forceinline__ float softplusf(float x) {
    return fmaxf(x, 0.0f) + log1pf(expf(-fabsf(x)));
}

__device__ __forceinline__ float sigmoidf(float x) {
    return 1.0f / (1.0f + expf(-x));
}

__device__ __forceinline__ float wave_sum(float v) {
    for (int off = 32; off > 0; off >>= 1) v += __shfl_down(v, off);
    return __shfl(v, 0);
}

// ---------------- kernel 1: per-(sample,chunk) plane reductions -------------
// partials[(b*NCHUNK + ch)*3 + {0:sum_sigmoid, 1:sum_logv_sel, 2:count_sel}]
__global__ __launch_bounds__(256) void plane_reduce(const float* __restrict__ out,
                                                    float* __restrict__ partials) {
    const int b  = blockIdx.x >> 5;      // / NCHUNK
    const int ch = blockIdx.x & 31;      // % NCHUNK
    const float4* plane = (const float4*)(out + (size_t)b * Cn * PLANE); // channel 0
    const int tid = threadIdx.x;
    const int i0  = ch * VPER + tid;

    // 4 guaranteed + 1 tail vector load per thread (1100 = 4*256 + 76)
    float4 v0 = plane[i0];
    float4 v1 = plane[i0 + 256];
    float4 v2 = plane[i0 + 512];
    float4 v3 = plane[i0 + 768];

    float s_sig = 0.0f, s_log = 0.0f, s_cnt = 0.0f;
    float xs[16];
    xs[0]=v0.x; xs[1]=v0.y; xs[2]=v0.z; xs[3]=v0.w;
    xs[4]=v1.x; xs[5]=v1.y; xs[6]=v1.z; xs[7]=v1.w;
    xs[8]=v2.x; xs[9]=v2.y; xs[10]=v2.z; xs[11]=v2.w;
    xs[12]=v3.x; xs[13]=v3.y; xs[14]=v3.z; xs[15]=v3.w;
    #pragma unroll
    for (int k = 0; k < 16; ++k) {
        float x = xs[k];
        float p = sigmoidf(x);
        s_sig += p;
        bool sel = p > BKG_THRESH;
        s_cnt += sel ? 1.0f : 0.0f;
        s_log += sel ? fmaxf(-softplusf(x), LOG_CLAMP) : 0.0f;
    }
    if (tid < VPER - 1024) {   // 76 tail threads
        float4 v4 = plane[i0 + 1024];
        float ys[4] = {v4.x, v4.y, v4.z, v4.w};
        #pragma unroll
        for (int k = 0; k < 4; ++k) {
            float x = ys[k];
            float p = sigmoidf(x);
            s_sig += p;
            bool sel = p > BKG_THRESH;
            s_cnt += sel ? 1.0f : 0.0f;
            s_log += sel ? fmaxf(-softplusf(x), LOG_CLAMP) : 0.0f;
        }
    }

    // wave reduce, then LDS across the 4 waves
    s_sig = wave_sum(s_sig);
    s_log = wave_sum(s_log);
    s_cnt = wave_sum(s_cnt);

    __shared__ float sh[4][3];
    const int wv = tid >> 6, lane = tid & 63;
    if (lane == 0) { sh[wv][0] = s_sig; sh[wv][1] = s_log; sh[wv][2] = s_cnt; }
    __syncthreads();
    if (tid == 0) {
        float a = sh[0][0] + sh[1][0] + sh[2][0] + sh[3][0];
        float c = sh[0][1] + sh[1][1] + sh[2][1] + sh[3][1];
        float d = sh[0][2] + sh[1][2] + sh[2][2] + sh[3][2];
        float* p = partials + (size_t)(b * NCHUNK + ch) * 3;
        p[0] = a; p[1] = c; p[2] = d;
    }
}

// ---------------- kernel 2: per-sample loss + batch finalize (1 block) ------
// 1024 threads = 16 waves; wave b handles sample b.
__global__ __launch_bounds__(1024) void sample_finalize(const float* __restrict__ out,
                                                        const float* __restrict__ tgt,
                                                        const float* __restrict__ partials,
                                                        float* __restrict__ out7) {
    const int b    = threadIdx.x >> 6;   // wave id = sample
    const int lane = threadIdx.x & 63;

    // ---- reduce plane partials (32 chunks) ----
    float s_sig = 0.0f, s_log = 0.0f, s_cnt = 0.0f;
    if (lane < NCHUNK) {
        const float* p = partials + (size_t)(b * NCHUNK + lane) * 3;
        s_sig = p[0]; s_log = p[1]; s_cnt = p[2];
    }
    s_sig = wave_sum(s_sig);
    s_log = wave_sum(s_log);
    s_cnt = wave_sum(s_cnt);

    // ---- load the 50 targets, one per lane ----
    const float* t = tgt + (size_t)b * Nn * 7;
    const bool active = lane < Nn;
    float tx = 0.0f, ty = 0.0f, t2 = 0.0f, t3 = 1.0f, t4 = 1.0f, t5 = 1.0f, ang = 0.0f;
    int key = -1;
    __shared__ int keys[Bn][64];
    if (active) {
        tx = t[lane * 7 + 0] * 2.0f;
        ty = t[lane * 7 + 1] * 2.0f;
        t2 = t[lane * 7 + 2];
        t3 = t[lane * 7 + 3];
        t4 = t[lane * 7 + 4];
        t5 = t[lane * 7 + 5];
        ang = t[lane * 7 + 6];
        int dx = (int)floorf(tx);
        int dy = (int)floorf(ty);
        key = dx * Wn + dy;
        keys[b][lane] = key;
    }
    __syncthreads();

    // first-occurrence dedupe (mask semantics: each unique cell masked once)
    bool isfirst = active;
    if (active) {
        for (int m = 0; m < lane; ++m) {
            if (keys[b][m] == key) { isfirst = false; break; }
        }
    }

    // ---- gather the 10 channels at the point ----
    const float* base = out + (size_t)b * Cn * PLANE;
    float g[10];
    #pragma unroll
    for (int c = 0; c < 10; ++c) g[c] = active ? base[(size_t)c * PLANE + key] : 0.0f;

    // ---- corrections for masked (unique) points ----
    float c_sig = 0.0f, c_log = 0.0f, c_cnt = 0.0f, c_n = 0.0f;
    if (isfirst) {
        float p = sigmoidf(g[0]);
        c_sig = p;
        c_n = 1.0f;
        if (p > BKG_THRESH) {
            c_cnt = 1.0f;
            c_log = fmaxf(-softplusf(g[0]), LOG_CLAMP);
        }
    }
    c_sig = wave_sum(c_sig);
    c_log = wave_sum(c_log);
    c_cnt = wave_sum(c_cnt);
    c_n   = wave_sum(c_n);

    // ---- per-point loss contributions (ALL 50 points, duplicates included) ----
    float v_obj = 0.0f, v_xyz = 0.0f, v_hwl = 0.0f, v_acl = 0.0f, v_asin = 0.0f;
    if (active) {
        v_obj = -fmaxf(-softplusf(-g[0]), LOG_CLAMP);

        float fx = tx - floorf(tx);
        float fy = ty - floorf(ty);
        float tz = t2 * 0.25f;                 // / ZSIZE (=4.0)
        float e0 = sigmoidf(g[1]) - fx;
        float e1 = sigmoidf(g[2]) - fy;
        float e2 = sigmoidf(g[3]) - tz;
        v_xyz = e0 * e0 + e1 * e1 + e2 * e2;

        float h0 = g[4] - logf(t3 / 1.52f);
        float h1 = g[5] - logf(t4 / 1.63f);
        float h2 = g[6] - logf(t5 / 3.88f);
        v_hwl = h0 * h0 + h1 * h1 + h2 * h2;

        float m = fmaxf(g[7], g[8]);
        float lse = m + logf(expf(g[7] - m) + expf(g[8] - m));
        float gsel = (ang >= 0.0f) ? g[8] : g[7];
        v_acl = lse - gsel;

        float d = sinf(g[9]) - sinf(sinf(ang));
        float ad = fabsf(d);
        v_asin = (ad < 1.0f) ? 0.5f * d * d : ad - 0.5f;
    }
    v_obj  = wave_sum(v_obj);
    v_xyz  = wave_sum(v_xyz);
    v_hwl  = wave_sum(v_hwl);
    v_acl  = wave_sum(v_acl);
    v_asin = wave_sum(v_asin);

    __shared__ float sh_terms[Bn][6];
    if (lane == 0) {
        float nbkg    = (float)PLANE - c_n;
        float sig_bkg = s_sig - c_sig;
        float clsscale = expf(-3.0f * sig_bkg / nbkg) * 2.5f;

        float cnt  = s_cnt - c_cnt;
        float slog = s_log - c_log;
        float bkg_l = (cnt > 0.0f) ? (-slog / fmaxf(cnt, 1.0f)) : 0.0f;

        const float invN  = 1.0f / (float)Nn;
        const float invN3 = 1.0f / (float)(Nn * 3);

        sh_terms[b][0] = bkg_l;
        sh_terms[b][1] = v_obj * invN * clsscale;
        sh_terms[b][2] = v_xyz * invN3;
        sh_terms[b][3] = v_hwl * invN3 * 0.5f;
        sh_terms[b][4] = v_acl * invN * 0.5f;
        sh_terms[b][5] = v_asin * invN * 0.5f;
    }
    __syncthreads();

    if (threadIdx.x == 0) {
        float s[6] = {0, 0, 0, 0, 0, 0};
        for (int bb = 0; bb < Bn; ++bb)
            for (int j = 0; j < 6; ++j)
                s[j] += sh_terms[bb][j];
        float tot = 0.0f;
        for (int j = 0; j < 6; ++j) tot += s[j];
        out7[0] = tot;
        for (int j = 0; j < 6; ++j) out7[1 + j] = s[j];
    }
}

extern "C" void kernel_launch(void* const* d_in, const int* in_sizes, int n_in,
                              void* d_out, int out_size, void* d_ws, size_t ws_size,
                              hipStream_t stream) {
    const float* out = (const float*)d_in[0];   // (B, C, H, W) f32
    const float* tgt = (const float*)d_in[1];   // (B, N, 7)   f32
    float* o  = (float*)d_out;                  // 7 floats
    float* ws = (float*)d_ws;

    float* partials = ws;          // Bn*NCHUNK*3 = 1536 floats

    plane_reduce<<<Bn * NCHUNK, 256, 0, stream>>>(out, partials);
    sample_finalize<<<1, 1024, 0, stream>>>(out, tgt, partials, o);
}